// Round 4
// baseline (55.807 us; speedup 1.0000x reference)
//
#include <hip/hip_runtime.h>
#include <hip/hip_bf16.h>
#include <math.h>

#define NVOX 262144   // 64^3
#define BIGF 1e8f

// ---- helpers ----
__device__ __forceinline__ unsigned short f2bf(float x) {
    __hip_bfloat16 h = __float2bfloat16(x);
    return *reinterpret_cast<unsigned short*>(&h);
}
__device__ __forceinline__ float bf2f(unsigned short u) {
    __hip_bfloat16 h = *reinterpret_cast<__hip_bfloat16*>(&u);
    return __bfloat162float(h);
}
// squared distance (u16, 0xFFFF = +inf) from lane w to nearest set bit of mask
__device__ __forceinline__ unsigned short dist2_u16(unsigned long long mask, int w) {
    if (mask == 0ull) return 0xFFFFu;
    unsigned long long mr = mask >> w;          // bits k >= w
    unsigned long long ml = mask << (63 - w);   // bits k <= w
    int dr = mr ? __builtin_ctzll(mr) : 127;
    int dl = ml ? __builtin_clzll(ml) : 127;
    int dd = dr < dl ? dr : dl;
    return (unsigned short)(dd * dd);
}

// =====================================================================
// kA: pure streaming. grid = 1024 (b x 256 segs of 1024 voxels), 256 thr.
// Softmax stats partials + bf16 probs written to probsT[combo][h][d][w]
// (for natural-order voxels these addresses are contiguous in w => coalesced).
// =====================================================================
__global__ __launch_bounds__(256) void kA_stats_probs(
    const float* __restrict__ preds, const int* __restrict__ targets,
    unsigned short* __restrict__ probsT, float* __restrict__ part_stats) {
    __shared__ float sred[4 * 13];
    int blk = blockIdx.x;
    int b = blk >> 8, seg = blk & 255;
    int t = threadIdx.x, lane = t & 63, wid = t >> 6;
    size_t vbase = (size_t)seg * 1024 + 4 * t;            // within volume
    const float* p = preds + (size_t)(b * 4) * NVOX + vbase;
    float4 x0 = *(const float4*)(p);
    float4 x1 = *(const float4*)(p + NVOX);
    float4 x2 = *(const float4*)(p + 2 * NVOX);
    float4 x3 = *(const float4*)(p + 3 * NVOX);
    int4 tv4 = *(const int4*)(targets + (size_t)b * NVOX + vbase);

    float q[13];
    #pragma unroll
    for (int k = 0; k < 13; ++k) q[k] = 0.0f;
    unsigned short pb[3][4];

    #pragma unroll
    for (int j = 0; j < 4; ++j) {
        float a0 = (&x0.x)[j], a1 = (&x1.x)[j], a2 = (&x2.x)[j], a3 = (&x3.x)[j];
        int tv = (&tv4.x)[j];
        float m  = fmaxf(fmaxf(a0, a1), fmaxf(a2, a3));
        float e0 = expf(a0 - m), e1 = expf(a1 - m), e2 = expf(a2 - m), e3 = expf(a3 - m);
        float ssum = e0 + e1 + e2 + e3;
        float inv  = 1.0f / ssum;
        float p0 = e0 * inv, p1 = e1 * inv, p2 = e2 * inv, p3 = e3 * inv;
        float xt = (tv == 0) ? a0 : (tv == 1) ? a1 : (tv == 2) ? a2 : a3;
        q[12] += -(xt - m - logf(ssum));
        q[4] += p0; q[5] += p1; q[6] += p2; q[7] += p3;
        if (tv == 0)      { q[0] += p0; q[8]  += 1.0f; }
        else if (tv == 1) { q[1] += p1; q[9]  += 1.0f; }
        else if (tv == 2) { q[2] += p2; q[10] += 1.0f; }
        else              { q[3] += p3; q[11] += 1.0f; }
        pb[0][j] = f2bf(p1); pb[1][j] = f2bf(p2); pb[2][j] = f2bf(p3);
    }

    // probsT[combo][h][d][w]: voxel v -> h*4096 + d*64 + w (4 consecutive w)
    int v0 = (int)vbase;
    int d = v0 >> 12, h = (v0 >> 6) & 63, w0 = v0 & 63;
    size_t poff = (size_t)h * 4096 + d * 64 + w0;
    #pragma unroll
    for (int c = 0; c < 3; ++c) {
        ushort4 u = make_ushort4(pb[c][0], pb[c][1], pb[c][2], pb[c][3]);
        *(ushort4*)(probsT + (size_t)(b * 3 + c) * NVOX + poff) = u;
    }

    #pragma unroll
    for (int k = 0; k < 13; ++k) {
        float x = q[k];
        #pragma unroll
        for (int o = 32; o > 0; o >>= 1) x += __shfl_down(x, o);
        if (lane == 0) sred[wid * 13 + k] = x;
    }
    __syncthreads();
    if (t < 13) {
        float s = sred[t] + sred[13 + t] + sred[26 + t] + sred[39 + t];
        part_stats[t * 1024 + blk] = s;
    }
}

// =====================================================================
// kB: EDT pass-1 (W, ballot) + pass-2 (H, early-exit scan in LDS).
// grid = 768 (b*192 + d*3 + cm), 256 thr. Reads targets only.
// Writes bufA[combo + 12*v][h][d][w] (u16 squared dist, 0xFFFF = inf).
// =====================================================================
__global__ __launch_bounds__(256) void kB_edt12(
    const int* __restrict__ targets, unsigned short* __restrict__ bufA) {
    __shared__ float tO[64 * 65];
    __shared__ float tI[64 * 65];
    int blk = blockIdx.x;
    int cm = blk % 3;
    int bd = blk / 3;            // b*64 + d
    int d = bd & 63, b = bd >> 6;
    int c = cm + 1;
    int t = threadIdx.x, lane = t & 63, wid = t >> 6;
    const int* tg = targets + (size_t)b * NVOX + (size_t)d * 4096;

    // pass-1 along W via ballot (wave = one W-line, lane = w)
    #pragma unroll
    for (int i = 0; i < 16; ++i) {
        int e = t + 256 * i;
        int h = wid + 4 * i;
        int tv = tg[e];
        unsigned long long mask = __ballot(tv == c);
        unsigned short o  = dist2_u16(mask, lane);
        unsigned short ii = dist2_u16(~mask, lane);
        tO[h * 65 + lane] = (o  == 0xFFFFu) ? BIGF : (float)o;
        tI[h * 65 + lane] = (ii == 0xFFFFu) ? BIGF : (float)ii;
    }
    __syncthreads();

    // pass-2 along H: wave owns 16 cols w = wid*16+r; lane = h. Early-exit.
    float hf = (float)lane;
    for (int r = 0; r < 16; ++r) {
        int w = wid * 16 + r;
        {
            float best = tO[lane * 65 + w];
            for (int dk = 1; dk < 64; ++dk) {
                float d2 = (float)(dk * dk);
                if (__all(d2 >= best)) break;
                int hl = lane - dk; hl = hl < 0 ? 0 : hl;
                int hr = lane + dk; hr = hr > 63 ? 63 : hr;
                best = fminf(fminf(best, tO[hl * 65 + w] + d2), tO[hr * 65 + w] + d2);
            }
            tO[lane * 65 + w] = best;   // wave-lockstep: safe in-place
        }
        {
            float best = tI[lane * 65 + w];
            for (int dk = 1; dk < 64; ++dk) {
                float d2 = (float)(dk * dk);
                if (__all(d2 >= best)) break;
                int hl = lane - dk; hl = hl < 0 ? 0 : hl;
                int hr = lane + dk; hr = hr > 63 ? 63 : hr;
                best = fminf(fminf(best, tI[hl * 65 + w] + d2), tI[hr * 65 + w] + d2);
            }
            tI[lane * 65 + w] = best;
        }
    }
    __syncthreads();

    // write planes: bufA[combo_v][h][d][w], per-row 128B coalesced
    int combo = b * 3 + cm;
    size_t oO = (size_t)combo * NVOX + (size_t)d * 64;
    size_t oI = (size_t)(combo + 12) * NVOX + (size_t)d * 64;
    #pragma unroll
    for (int i = 0; i < 16; ++i) {
        int h = wid + 4 * i;
        float vo = tO[h * 65 + lane];
        float vi = tI[h * 65 + lane];
        bufA[oO + (size_t)h * 4096 + lane] = (vo >= 1e7f) ? 0xFFFFu : (unsigned short)vo;
        bufA[oI + (size_t)h * 4096 + lane] = (vi >= 1e7f) ? 0xFFFFu : (unsigned short)vi;
    }
}

// =====================================================================
// k2: EDT pass-3 (D, early-exit scan) + sdf*prob reduce.
// grid = 768 (combo*64 + h), 512 thr. All global accesses contiguous.
// =====================================================================
__global__ __launch_bounds__(512) void k2_edt3_sdf(
    const unsigned short* __restrict__ bufA, const unsigned short* __restrict__ probsT,
    float* __restrict__ part_bound) {
    __shared__ float pl[2][64 * 65];
    __shared__ float sredb[8];
    int blk = blockIdx.x;
    int combo = blk >> 6, h = blk & 63;
    int t = threadIdx.x, lane = t & 63, wid = t >> 6;

    for (int v = 0; v < 2; ++v) {
        const unsigned short* src = bufA + (size_t)(combo + 12 * v) * NVOX + (size_t)h * 4096;
        #pragma unroll
        for (int i = 0; i < 8; ++i) {
            int e = t + 512 * i;                     // e = d*64 + w
            unsigned short u = src[e];
            pl[v][e + (e >> 6)] = (u == 0xFFFFu) ? BIGF : (float)u;   // lds[d*65+w]
        }
    }
    __syncthreads();

    // pass along D: wave owns cols w = wid*8+r; lane = d. Early-exit.
    for (int v = 0; v < 2; ++v) {
        for (int r = 0; r < 8; ++r) {
            int w = wid * 8 + r;
            float* col = &pl[v][w];
            float best = col[lane * 65];
            for (int dk = 1; dk < 64; ++dk) {
                float d2 = (float)(dk * dk);
                if (__all(d2 >= best)) break;
                int dl = lane - dk; dl = dl < 0 ? 0 : dl;
                int dr = lane + dk; dr = dr > 63 ? 63 : dr;
                best = fminf(fminf(best, col[dl * 65] + d2), col[dr * 65] + d2);
            }
            col[lane * 65] = best;
        }
    }
    __syncthreads();

    const unsigned short* pp = probsT + (size_t)combo * NVOX + (size_t)h * 4096;
    float acc = 0.0f;
    #pragma unroll
    for (int i = 0; i < 8; ++i) {
        int e = t + 512 * i;
        int li = e + (e >> 6);
        float sdf = sqrtf(pl[0][li]) - sqrtf(pl[1][li]);
        acc += sdf * bf2f(pp[e]);
    }
    #pragma unroll
    for (int o = 32; o > 0; o >>= 1) acc += __shfl_down(acc, o);
    if (lane == 0) sredb[wid] = acc;
    __syncthreads();
    if (t == 0) {
        float s = 0.0f;
        for (int j = 0; j < 8; ++j) s += sredb[j];
        part_bound[blk] = s;
    }
}

// =====================================================================
// k3: single block. Reduce partials (f64), guards, assemble scalar.
// =====================================================================
__global__ __launch_bounds__(1024) void k3_final(
    const float* __restrict__ part_stats, const float* __restrict__ part_bound,
    float* __restrict__ out) {
    __shared__ float sred[13 * 16];
    __shared__ double S[13 * 4];
    __shared__ double BND[12];
    int t = threadIdx.x, lane = t & 63, wid = t >> 6;

    for (int k = 0; k < 13; ++k) {
        float v = part_stats[k * 1024 + t];
        #pragma unroll
        for (int o = 32; o > 0; o >>= 1) v += __shfl_down(v, o);
        if (lane == 0) sred[k * 16 + wid] = v;
    }
    __syncthreads();
    if (t < 52) {               // k = t>>2, b = t&3; 4 waves per b
        int k = t >> 2, b = t & 3;
        double s = (double)sred[k * 16 + b * 4] + (double)sred[k * 16 + b * 4 + 1]
                 + (double)sred[k * 16 + b * 4 + 2] + (double)sred[k * 16 + b * 4 + 3];
        S[k * 4 + b] = s;
    }
    if (t < 768) {              // wave id = combo (64 h-entries each)
        float v = part_bound[t];
        #pragma unroll
        for (int o = 32; o > 0; o >>= 1) v += __shfl_down(v, o);
        if (lane == 0) BND[wid] = (double)v;
    }
    __syncthreads();
    if (t == 0) {
        const double NV = (double)NVOX;
        double dice_sum = 0.0;
        for (int b = 0; b < 4; ++b)
            for (int c = 0; c < 4; ++c) {
                double inter = S[c * 4 + b];
                double un    = S[(4 + c) * 4 + b] + S[(8 + c) * 4 + b];
                dice_sum += (2.0 * inter + 1e-5) / (un + 1e-5);
            }
        double l_dice = 1.0 - dice_sum / 16.0;
        double l_ce = (S[48] + S[49] + S[50] + S[51]) / (4.0 * NV);
        double lb = 0.0;
        for (int combo = 0; combo < 12; ++combo) {
            int b = combo / 3, c = combo % 3 + 1;
            double cnt = S[(8 + c) * 4 + b];
            double s;
            if (cnt == 0.0)      s =  S[(4 + c) * 4 + b];   // sdf == +1 everywhere
            else if (cnt == NV)  s = -S[(4 + c) * 4 + b];   // sdf == -1 everywhere
            else                 s =  BND[combo];
            lb += s / NV;
        }
        lb /= 12.0;
        out[0] = (float)(l_dice + l_ce + 0.01 * lb);
    }
}

extern "C" void kernel_launch(void* const* d_in, const int* in_sizes, int n_in,
                              void* d_out, int out_size, void* d_ws, size_t ws_size,
                              hipStream_t stream) {
    const float* preds   = (const float*)d_in[0];
    const int*   targets = (const int*)d_in[1];
    float* out = (float*)d_out;

    // workspace: bufA u16 (12.6 MB) | probsT bf16 (6.3 MB) | partials (~60 KB)
    unsigned short* bufA   = (unsigned short*)d_ws;
    unsigned short* probsT = bufA + (size_t)24 * NVOX;
    float* part_stats = (float*)(probsT + (size_t)12 * NVOX);
    float* part_bound = part_stats + 13 * 1024;

    kA_stats_probs<<<1024, 256, 0, stream>>>(preds, targets, probsT, part_stats);
    kB_edt12<<<768, 256, 0, stream>>>(targets, bufA);
    k2_edt3_sdf<<<768, 512, 0, stream>>>(bufA, probsT, part_bound);
    k3_final<<<1, 1024, 0, stream>>>(part_stats, part_bound, out);
}